// Round 13
// baseline (161.889 us; speedup 1.0000x reference)
//
#include <hip/hip_runtime.h>
#include <math.h>

#define NN 10000
#define EE 160000

// ---- workspace layout (float indices) ----
#define OFF_WTT 0            // [6][64][64] f32 (WtT[k][c][d] = Wt_k[d][c])   len 24576
#define OFF_PK  24576        // packed f16 MLP weights, 34816 u16             len 17408
#define OFF_B2P 41984        // permuted bs2 f32 [192]                        len 192
#define OFF_IASH 42176       // [N][5][64] u32 packed fp16 pairs              len 3200000
#define OFF_EAH 3242176      // [E][3][64] f16 (ch' = comp*64+unit)           len 15360000
#define OFF_INT 18602176     // counts[N] cursor[N] offsets[N+1] bucket[E] dstp[E]

typedef __attribute__((ext_vector_type(8))) _Float16 h16x8;
typedef __attribute__((ext_vector_type(2))) __fp16 fp16x2_raw;
typedef __attribute__((ext_vector_type(4))) float f32x4;

__device__ __forceinline__ float silu_f(float x) {
    return x * __builtin_amdgcn_rcpf(1.0f + __expf(-x));
}
__device__ __forceinline__ unsigned int pkh(float a, float b) {
    union { fp16x2_raw h; unsigned int u; } cv;
    cv.h = __builtin_amdgcn_cvt_pkrtz(a, b);
    return cv.u;
}
__device__ __forceinline__ unsigned short f2h(float f) {
    union { _Float16 h; unsigned short u; } cv; cv.h = (_Float16)f; return cv.u;
}
__device__ __forceinline__ float h2f(unsigned short s) {
    union { unsigned short u; _Float16 h; } cv; cv.u = s; return (float)cv.h;
}
__device__ __forceinline__ float h2f_lo(unsigned int u) { return h2f((unsigned short)(u & 0xffffu)); }
__device__ __forceinline__ float h2f_hi(unsigned int u) { return h2f((unsigned short)(u >> 16)); }
__device__ __forceinline__ unsigned int bperm(int addr, unsigned int v) {
    return (unsigned int)__builtin_amdgcn_ds_bpermute(addr, (int)v);
}

// ---------------- prep: Wt transpose + f16 weight pack + bs2 permute + degree count ----------------
__global__ void k_prep(const float* __restrict__ Wt0, const float* __restrict__ Wt1,
                       const float* __restrict__ Wt2, const float* __restrict__ Wt3,
                       const float* __restrict__ Wt4, const float* __restrict__ Wt5,
                       const float* __restrict__ Ws0, const float* __restrict__ Ws1,
                       const float* __restrict__ Ws2, const float* __restrict__ bs2,
                       const int* __restrict__ ei,
                       float* __restrict__ WtT, unsigned short* __restrict__ PK,
                       float* __restrict__ bs2p, int* __restrict__ counts) {
    int idx = blockIdx.x * 256 + threadIdx.x;
    if (idx < 24576) {
        int k = idx >> 12, r = idx & 4095;
        int c = r >> 6, d = r & 63;
        const float* W = (k == 0) ? Wt0 : (k == 1) ? Wt1 : (k == 2) ? Wt2
                       : (k == 3) ? Wt3 : (k == 4) ? Wt4 : Wt5;
        WtT[idx] = W[d * 64 + c];
    } else if (idx < 26624) {            // P1: Ws0 [64 out][32 in]
        int q = idx - 24576;
        int ot = q >> 9, r = q & 511, lane = r >> 3, j = r & 7;
        int k = ((lane >> 4) * 8) + j, o = ot * 16 + (lane & 15);
        PK[q] = f2h(Ws0[o * 32 + k]);
    } else if (idx < 34816) {            // P2: Ws1 [128][64]
        int q = idx - 24576;
        int i = q - 2048, ch = i >> 9, r = i & 511, lane = r >> 3, j = r & 7;
        int ot = ch >> 1, ks = ch & 1;
        int k = ks * 32 + (lane >> 4) * 8 + j, o = ot * 16 + (lane & 15);
        PK[q] = f2h(Ws1[o * 64 + k]);
    } else if (idx < 59392) {            // P3: Ws2 [192][128], rows permuted ch'=comp*64+unit
        int q = idx - 24576;
        int i = q - 10240, ch = i >> 9, r = i & 511, lane = r >> 3, j = r & 7;
        int ot = ch >> 2, ks = ch & 3;
        int k = ks * 32 + (lane >> 4) * 8 + j;
        int op = ot * 16 + (lane & 15);
        int o = (op & 63) * 3 + (op >> 6);
        PK[q] = f2h(Ws2[o * 128 + k]);
    } else if (idx < 59584) {
        int op = idx - 59392;
        bs2p[op] = bs2[(op & 63) * 3 + (op >> 6)];
    } else if (idx < 59584 + EE) {
        int e = idx - 59584;
        atomicAdd(&counts[ei[e]], 1);
    }
}

// ---------------- CSR scan ----------------
__global__ __launch_bounds__(256) void k_scan(const int* __restrict__ counts,
                                              int* __restrict__ offsets) {
    __shared__ int sums[256];
    int t = threadIdx.x;
    int base = t * 40;
    int s = 0;
    if (base < NN) {
        const int4* p = (const int4*)(counts + base);
#pragma unroll
        for (int q = 0; q < 10; ++q) { int4 a = p[q]; s += a.x + a.y + a.z + a.w; }
    }
    sums[t] = s;
    __syncthreads();
    for (int off = 1; off < 256; off <<= 1) {
        int tmp = (t >= off) ? sums[t - off] : 0;
        __syncthreads();
        sums[t] += tmp;
        __syncthreads();
    }
    int run = sums[t] - s;
    if (base < NN) {
        const int4* p = (const int4*)(counts + base);
#pragma unroll
        for (int q = 0; q < 10; ++q) {
            int4 a = p[q];
            offsets[base + 4 * q + 0] = run; run += a.x;
            offsets[base + 4 * q + 1] = run; run += a.y;
            offsets[base + 4 * q + 2] = run; run += a.z;
            offsets[base + 4 * q + 3] = run; run += a.w;
        }
    }
    if (t == 255) offsets[NN] = run;
}

// ---------------- CSR fill (light: bucket + dstp only) ----------------
__global__ void k_fill(const int* __restrict__ ei, const int* __restrict__ offsets,
                       int* __restrict__ cursor, int* __restrict__ bucket,
                       int* __restrict__ dstp) {
    int e = blockIdx.x * 256 + threadIdx.x;
    if (e < EE) {
        int s = ei[e];
        int pos = offsets[s] + atomicAdd(&cursor[s], 1);
        bucket[pos] = e;
        dstp[pos] = ei[EE + e];
    }
}

// ---------------- node prep: 4 nodes/block, 1 wave/node ----------------
__global__ __launch_bounds__(256) void k_nodeprep(const float* __restrict__ X,
                                                  const float* __restrict__ WtT,
                                                  unsigned int* __restrict__ IASu) {
    int t = threadIdx.x, w = t >> 6, c = t & 63;
    int n = blockIdx.x * 4 + w;
    __shared__ float XS[4][576];
    __shared__ float L[4][64][12];
    float* xs = XS[w];
#pragma unroll
    for (int i = 0; i < 9; i++) xs[c + 64 * i] = X[(size_t)n * 576 + c + 64 * i];
    __builtin_amdgcn_wave_barrier();
    float x[9];
#pragma unroll
    for (int j = 0; j < 9; j++) x[j] = xs[c * 9 + j];
    float nrm = 0.f;
#pragma unroll
    for (int j = 0; j < 9; j++) nrm += x[j] * x[j];
    float inv = __builtin_amdgcn_rcpf(nrm + 1.0f);
#pragma unroll
    for (int j = 0; j < 9; j++) x[j] *= inv;
    float tr3 = (x[0] + x[4] + x[8]) * (1.0f / 3.0f);
    L[w][c][0] = tr3;
    L[w][c][1] = 0.5f * (x[1] - x[3]);
    L[w][c][2] = 0.5f * (x[2] - x[6]);
    L[w][c][3] = 0.5f * (x[5] - x[7]);
    L[w][c][4] = x[0] - tr3;
    L[w][c][5] = x[4] - tr3;
    L[w][c][6] = 0.5f * (x[1] + x[3]);
    L[w][c][7] = 0.5f * (x[2] + x[6]);
    L[w][c][8] = 0.5f * (x[5] + x[7]);
    __builtin_amdgcn_wave_barrier();
    int d = c;
    const float* W0 = WtT;
    const float* W1 = WtT + 4096;
    const float* W2 = WtT + 8192;
    float aI = 0, aA0 = 0, aA1 = 0, aA2 = 0, aS0 = 0, aS1 = 0, aS2 = 0, aS3 = 0, aS4 = 0;
    for (int cc = 0; cc < 64; ++cc) {
        float w0 = W0[cc * 64 + d], w1 = W1[cc * 64 + d], w2 = W2[cc * 64 + d];
        float4 L0 = *(const float4*)&L[w][cc][0];
        float4 L1 = *(const float4*)&L[w][cc][4];
        float L8 = L[w][cc][8];
        aI  += w0 * L0.x;
        aA0 += w1 * L0.y; aA1 += w1 * L0.z; aA2 += w1 * L0.w;
        aS0 += w2 * L1.x; aS1 += w2 * L1.y; aS2 += w2 * L1.z;
        aS3 += w2 * L1.w; aS4 += w2 * L8;
    }
    unsigned int* op = IASu + (size_t)n * 320 + d;
    op[0]   = pkh(aI, aA0);
    op[64]  = pkh(aA1, aA2);
    op[128] = pkh(aS0, aS1);
    op[192] = pkh(aS2, aS3);
    op[256] = pkh(aS4, 0.0f);
}

// ---------------- edge MLP: fp16 MFMA, no LDS (bpermute transpose), original edge order ----------------
__global__ __launch_bounds__(256) void k_mlp(const float* __restrict__ attr,
                                             const float* __restrict__ ew,
                                             const unsigned short* __restrict__ PK,
                                             const float* __restrict__ bs0,
                                             const float* __restrict__ bs1,
                                             const float* __restrict__ bs2p,
                                             unsigned short* __restrict__ eah) {
    int t = threadIdx.x, w = t >> 6, l = t & 63;
    int e = l & 15, lg = l >> 4;
    int pos = blockIdx.x * 64 + w * 16 + e;
    const h16x8* P1 = (const h16x8*)PK;
    const h16x8* P2 = (const h16x8*)(PK + 2048);
    const h16x8* P3 = (const h16x8*)(PK + 10240);
    union U8 { h16x8 h; unsigned int u[4]; uint4 v; };
    U8 B1;
    {
        const float* ap = attr + (size_t)pos * 32 + lg * 8;
        float4 a0 = *(const float4*)ap;
        float4 a1 = *(const float4*)(ap + 4);
        B1.u[0] = pkh(a0.x, a0.y); B1.u[1] = pkh(a0.z, a0.w);
        B1.u[2] = pkh(a1.x, a1.y); B1.u[3] = pkh(a1.z, a1.w);
    }
    float rw = ew[pos];
    float C = (rw < 1.0f) ? 0.5f * (cosf(3.14159265358979f * rw) + 1.0f) : 0.0f;
    int src0 = ((lg & 1) * 32 + e) * 4;
    int src1 = src0 + 64;
    bool hi = (lg >= 2);

    unsigned int h01[8], h23[8];
    // ---- layer 1: 32 -> 64 ----
#pragma unroll
    for (int ot = 0; ot < 4; ++ot) {
        float4 bb = *(const float4*)&bs0[ot * 16 + lg * 4];
        f32x4 acc = {bb.x, bb.y, bb.z, bb.w};
        acc = __builtin_amdgcn_mfma_f32_16x16x32_f16(P1[ot * 64 + l], B1.h, acc, 0, 0, 0);
        h01[ot] = pkh(silu_f(acc[0]), silu_f(acc[1]));
        h23[ot] = pkh(silu_f(acc[2]), silu_f(acc[3]));
    }
    // ---- transpose -> B2a (ch 0-31), B2b (ch 32-63) ----
    U8 B2a, B2b;
    {
        unsigned int a, b;
        a = bperm(src0, h01[0]); b = bperm(src0, h01[1]); B2a.u[0] = hi ? b : a;
        a = bperm(src0, h23[0]); b = bperm(src0, h23[1]); B2a.u[1] = hi ? b : a;
        a = bperm(src1, h01[0]); b = bperm(src1, h01[1]); B2a.u[2] = hi ? b : a;
        a = bperm(src1, h23[0]); b = bperm(src1, h23[1]); B2a.u[3] = hi ? b : a;
        a = bperm(src0, h01[2]); b = bperm(src0, h01[3]); B2b.u[0] = hi ? b : a;
        a = bperm(src0, h23[2]); b = bperm(src0, h23[3]); B2b.u[1] = hi ? b : a;
        a = bperm(src1, h01[2]); b = bperm(src1, h01[3]); B2b.u[2] = hi ? b : a;
        a = bperm(src1, h23[2]); b = bperm(src1, h23[3]); B2b.u[3] = hi ? b : a;
    }
    // ---- layer 2: 64 -> 128 ----
#pragma unroll
    for (int ot = 0; ot < 8; ++ot) {
        float4 bb = *(const float4*)&bs1[ot * 16 + lg * 4];
        f32x4 acc = {bb.x, bb.y, bb.z, bb.w};
        acc = __builtin_amdgcn_mfma_f32_16x16x32_f16(P2[(ot * 2 + 0) * 64 + l], B2a.h, acc, 0, 0, 0);
        acc = __builtin_amdgcn_mfma_f32_16x16x32_f16(P2[(ot * 2 + 1) * 64 + l], B2b.h, acc, 0, 0, 0);
        h01[ot] = pkh(silu_f(acc[0]), silu_f(acc[1]));
        h23[ot] = pkh(silu_f(acc[2]), silu_f(acc[3]));
    }
    // ---- transpose -> B3[4] (ch ks*32 .. +31) ----
    U8 B3[4];
#pragma unroll
    for (int ks = 0; ks < 4; ++ks) {
        unsigned int a, b;
        a = bperm(src0, h01[ks * 2]); b = bperm(src0, h01[ks * 2 + 1]); B3[ks].u[0] = hi ? b : a;
        a = bperm(src0, h23[ks * 2]); b = bperm(src0, h23[ks * 2 + 1]); B3[ks].u[1] = hi ? b : a;
        a = bperm(src1, h01[ks * 2]); b = bperm(src1, h01[ks * 2 + 1]); B3[ks].u[2] = hi ? b : a;
        a = bperm(src1, h23[ks * 2]); b = bperm(src1, h23[ks * 2 + 1]); B3[ks].u[3] = hi ? b : a;
    }
    // ---- layer 3: 128 -> 192 (permuted channels), scale by C ----
    size_t ebase = (size_t)pos * 192;
#pragma unroll
    for (int ot = 0; ot < 12; ++ot) {
        float4 bb = *(const float4*)&bs2p[ot * 16 + lg * 4];
        f32x4 acc = {bb.x, bb.y, bb.z, bb.w};
        acc = __builtin_amdgcn_mfma_f32_16x16x32_f16(P3[(ot * 4 + 0) * 64 + l], B3[0].h, acc, 0, 0, 0);
        acc = __builtin_amdgcn_mfma_f32_16x16x32_f16(P3[(ot * 4 + 1) * 64 + l], B3[1].h, acc, 0, 0, 0);
        acc = __builtin_amdgcn_mfma_f32_16x16x32_f16(P3[(ot * 4 + 2) * 64 + l], B3[2].h, acc, 0, 0, 0);
        acc = __builtin_amdgcn_mfma_f32_16x16x32_f16(P3[(ot * 4 + 3) * 64 + l], B3[3].h, acc, 0, 0, 0);
        unsigned int u01 = pkh(silu_f(acc[0]) * C, silu_f(acc[1]) * C);
        unsigned int u23 = pkh(silu_f(acc[2]) * C, silu_f(acc[3]) * C);
        *(uint2*)&eah[ebase + ot * 16 + lg * 4] = make_uint2(u01, u23);
    }
}

// ---------------- fused aggregation + output: 4 nodes/block, 1 wave/node, 8-edge unroll ----------------
__global__ __launch_bounds__(256) void k_aggout(const int* __restrict__ offsets,
                                                const int* __restrict__ bucket,
                                                const int* __restrict__ dstp,
                                                const unsigned short* __restrict__ eah,
                                                const unsigned int* __restrict__ IASu,
                                                const float* __restrict__ X,
                                                const float* __restrict__ WtT,
                                                float* __restrict__ out) {
    int t = threadIdx.x, w = t >> 6, c = t & 63;
    int n = blockIdx.x * 4 + w;
    __shared__ float XS[4][576];
    __shared__ float LO[4][768];
    float* xs = XS[w];
    float* lo = LO[w];
#pragma unroll
    for (int i = 0; i < 9; i++) xs[c + 64 * i] = X[(size_t)n * 576 + c + 64 * i];

    int beg = offsets[n], end = offsets[n + 1];
    float m0 = 0, m1 = 0, m2 = 0, m3 = 0, m4 = 0, m5 = 0, m6 = 0, m7 = 0, m8 = 0;
    int i = beg;
    for (; i + 8 <= end; i += 8) {
        float a[8][3];
        unsigned int u[8][5];
#pragma unroll
        for (int q = 0; q < 8; ++q) {
            const unsigned short* ep = eah + (size_t)bucket[i + q] * 192;
            a[q][0] = h2f(ep[c]); a[q][1] = h2f(ep[64 + c]); a[q][2] = h2f(ep[128 + c]);
            const unsigned int* p = IASu + (size_t)dstp[i + q] * 320 + c;
            u[q][0] = p[0]; u[q][1] = p[64]; u[q][2] = p[128]; u[q][3] = p[192]; u[q][4] = p[256];
        }
#pragma unroll
        for (int q = 0; q < 8; ++q) {
            m0 += a[q][0] * h2f_lo(u[q][0]); m1 += a[q][1] * h2f_hi(u[q][0]);
            m2 += a[q][1] * h2f_lo(u[q][1]); m3 += a[q][1] * h2f_hi(u[q][1]);
            m4 += a[q][2] * h2f_lo(u[q][2]); m5 += a[q][2] * h2f_hi(u[q][2]);
            m6 += a[q][2] * h2f_lo(u[q][3]); m7 += a[q][2] * h2f_hi(u[q][3]);
            m8 += a[q][2] * h2f_lo(u[q][4]);
        }
    }
    for (; i + 4 <= end; i += 4) {
        float a[4][3];
        unsigned int u[4][5];
#pragma unroll
        for (int q = 0; q < 4; ++q) {
            const unsigned short* ep = eah + (size_t)bucket[i + q] * 192;
            a[q][0] = h2f(ep[c]); a[q][1] = h2f(ep[64 + c]); a[q][2] = h2f(ep[128 + c]);
            const unsigned int* p = IASu + (size_t)dstp[i + q] * 320 + c;
            u[q][0] = p[0]; u[q][1] = p[64]; u[q][2] = p[128]; u[q][3] = p[192]; u[q][4] = p[256];
        }
#pragma unroll
        for (int q = 0; q < 4; ++q) {
            m0 += a[q][0] * h2f_lo(u[q][0]); m1 += a[q][1] * h2f_hi(u[q][0]);
            m2 += a[q][1] * h2f_lo(u[q][1]); m3 += a[q][1] * h2f_hi(u[q][1]);
            m4 += a[q][2] * h2f_lo(u[q][2]); m5 += a[q][2] * h2f_hi(u[q][2]);
            m6 += a[q][2] * h2f_lo(u[q][3]); m7 += a[q][2] * h2f_hi(u[q][3]);
            m8 += a[q][2] * h2f_lo(u[q][4]);
        }
    }
    for (; i < end; ++i) {
        const unsigned short* ep = eah + (size_t)bucket[i] * 192;
        float a0 = h2f(ep[c]), a1 = h2f(ep[64 + c]), a2 = h2f(ep[128 + c]);
        const unsigned int* p = IASu + (size_t)dstp[i] * 320 + c;
        unsigned int u0 = p[0], u1 = p[64], u2 = p[128], u3 = p[192], u4 = p[256];
        m0 += a0 * h2f_lo(u0); m1 += a1 * h2f_hi(u0);
        m2 += a1 * h2f_lo(u1); m3 += a1 * h2f_hi(u1);
        m4 += a2 * h2f_lo(u2); m5 += a2 * h2f_hi(u2);
        m6 += a2 * h2f_lo(u3); m7 += a2 * h2f_hi(u3);
        m8 += a2 * h2f_lo(u4);
    }
    const unsigned int* yp = IASu + (size_t)n * 320 + c;
    unsigned int y0 = yp[0], y1 = yp[64], y2 = yp[128], y3 = yp[192], y4 = yp[256];
    float yI = h2f_lo(y0), yA0 = h2f_hi(y0), yA1 = h2f_lo(y1), yA2 = h2f_hi(y1);
    float yS0 = h2f_lo(y2), yS1 = h2f_hi(y2), yS2 = h2f_lo(y3), yS3 = h2f_hi(y3);
    float yS4 = h2f_lo(y4);

    float M[3][3] = {
        { m0 + m4,   m1 + m6,  m2 + m7 },
        { -m1 + m6,  m0 + m5,  m3 + m8 },
        { -m2 + m7, -m3 + m8,  m0 - m4 - m5 } };
    float Y[3][3] = {
        { yI + yS0,   yA0 + yS2,  yA1 + yS3 },
        { -yA0 + yS2, yI + yS1,   yA2 + yS4 },
        { -yA1 + yS3, -yA2 + yS4, yI - yS0 - yS1 } };
    float AB[3][3];
#pragma unroll
    for (int ii = 0; ii < 3; ii++)
#pragma unroll
        for (int j = 0; j < 3; j++) {
            float s = 0.f;
#pragma unroll
            for (int k = 0; k < 3; k++) s += M[ii][k] * Y[k][j] + Y[ii][k] * M[k][j];
            AB[ii][j] = s;
        }
    float tr3 = (AB[0][0] + AB[1][1] + AB[2][2]) * (1.0f / 3.0f);
    float fro = 0.f;
#pragma unroll
    for (int ii = 0; ii < 3; ii++)
#pragma unroll
        for (int j = 0; j < 3; j++) fro += AB[ii][j] * AB[ii][j];
    float inv = __builtin_amdgcn_rcpf(fro + 1.0f);
    float (*L12)[12] = (float (*)[12])lo;
    L12[c][0] = tr3 * inv;
    L12[c][1] = 0.5f * (AB[0][1] - AB[1][0]) * inv;
    L12[c][2] = 0.5f * (AB[0][2] - AB[2][0]) * inv;
    L12[c][3] = 0.5f * (AB[1][2] - AB[2][1]) * inv;
    L12[c][4] = (AB[0][0] - tr3) * inv;
    L12[c][5] = (AB[1][1] - tr3) * inv;
    L12[c][6] = 0.5f * (AB[0][1] + AB[1][0]) * inv;
    L12[c][7] = 0.5f * (AB[0][2] + AB[2][0]) * inv;
    L12[c][8] = 0.5f * (AB[1][2] + AB[2][1]) * inv;
    __builtin_amdgcn_wave_barrier();
    int d = c;
    const float* W3 = WtT + 3 * 4096;
    const float* W4 = WtT + 4 * 4096;
    const float* W5 = WtT + 5 * 4096;
    float aI = 0, aA0 = 0, aA1 = 0, aA2 = 0, aS0 = 0, aS1 = 0, aS2 = 0, aS3 = 0, aS4 = 0;
    for (int cc = 0; cc < 64; ++cc) {
        float w3 = W3[cc * 64 + d], w4 = W4[cc * 64 + d], w5 = W5[cc * 64 + d];
        float4 L0 = *(const float4*)&L12[cc][0];
        float4 L1 = *(const float4*)&L12[cc][4];
        float L8 = L12[cc][8];
        aI  += w3 * L0.x;
        aA0 += w4 * L0.y; aA1 += w4 * L0.z; aA2 += w4 * L0.w;
        aS0 += w5 * L1.x; aS1 += w5 * L1.y; aS2 += w5 * L1.z;
        aS3 += w5 * L1.w; aS4 += w5 * L8;
    }
    float dX[3][3] = {
        { aI + aS0,   aA0 + aS2,  aA1 + aS3 },
        { -aA0 + aS2, aI + aS1,   aA2 + aS4 },
        { -aA1 + aS3, -aA2 + aS4, aI - aS0 - aS1 } };
    float D2[3][3];
#pragma unroll
    for (int ii = 0; ii < 3; ii++)
#pragma unroll
        for (int j = 0; j < 3; j++) {
            float s = 0.f;
#pragma unroll
            for (int k = 0; k < 3; k++) s += dX[ii][k] * dX[k][j];
            D2[ii][j] = s;
        }
    float x[9];
    __builtin_amdgcn_wave_barrier();
#pragma unroll
    for (int j = 0; j < 9; j++) x[j] = xs[d * 9 + j];
    float nrm = 0.f;
#pragma unroll
    for (int j = 0; j < 9; j++) nrm += x[j] * x[j];
    float xinv = __builtin_amdgcn_rcpf(nrm + 1.0f);
    __builtin_amdgcn_wave_barrier();
#pragma unroll
    for (int ii = 0; ii < 3; ii++)
#pragma unroll
        for (int j = 0; j < 3; j++)
            lo[d * 9 + ii * 3 + j] = x[ii * 3 + j] * xinv + dX[ii][j] + D2[ii][j];
    __builtin_amdgcn_wave_barrier();
#pragma unroll
    for (int ii = 0; ii < 9; ii++) out[(size_t)n * 576 + c + 64 * ii] = lo[c + 64 * ii];
}

extern "C" void kernel_launch(void* const* d_in, const int* in_sizes, int n_in,
                              void* d_out, int out_size, void* d_ws, size_t ws_size,
                              hipStream_t stream) {
    (void)in_sizes; (void)n_in; (void)out_size; (void)ws_size;
    const int* ei = (const int*)d_in[0];
    const float* ew = (const float*)d_in[1];
    const float* attr = (const float*)d_in[2];
    const float* X = (const float*)d_in[3];
    const float* Ws0 = (const float*)d_in[4];
    const float* bs0 = (const float*)d_in[5];
    const float* Ws1 = (const float*)d_in[6];
    const float* bs1 = (const float*)d_in[7];
    const float* Ws2 = (const float*)d_in[8];
    const float* bs2 = (const float*)d_in[9];
    const float* Wt0 = (const float*)d_in[10];
    const float* Wt1 = (const float*)d_in[11];
    const float* Wt2 = (const float*)d_in[12];
    const float* Wt3 = (const float*)d_in[13];
    const float* Wt4 = (const float*)d_in[14];
    const float* Wt5 = (const float*)d_in[15];
    float* ws = (float*)d_ws;
    int* ibase = (int*)(ws + OFF_INT);
    int* counts = ibase;
    int* cursor = ibase + NN;
    int* offsets = ibase + 2 * NN;
    int* bucket = ibase + 3 * NN + 1;
    int* dstp = bucket + EE;
    unsigned short* PK = (unsigned short*)(ws + OFF_PK);
    unsigned int* IASu = (unsigned int*)(ws + OFF_IASH);
    unsigned short* eah = (unsigned short*)(ws + OFF_EAH);

    (void)hipMemsetAsync(counts, 0, 2 * NN * sizeof(int), stream);
    k_prep<<<(59584 + EE + 255) / 256, 256, 0, stream>>>(
        Wt0, Wt1, Wt2, Wt3, Wt4, Wt5, Ws0, Ws1, Ws2, bs2, ei,
        ws, PK, ws + OFF_B2P, counts);
    k_scan<<<1, 256, 0, stream>>>(counts, offsets);
    k_fill<<<(EE + 255) / 256, 256, 0, stream>>>(ei, offsets, cursor, bucket, dstp);
    k_nodeprep<<<NN / 4, 256, 0, stream>>>(X, ws, IASu);
    k_mlp<<<EE / 64, 256, 0, stream>>>(attr, ew, PK, bs0, bs1, ws + OFF_B2P, eah);
    k_aggout<<<NN / 4, 256, 0, stream>>>(offsets, bucket, dstp, eah, IASu, X, ws, (float*)d_out);
}

// Round 14
// 160.888 us; speedup vs baseline: 1.0062x; 1.0062x over previous
//
#include <hip/hip_runtime.h>
#include <math.h>

#define NN 10000
#define EE 160000

// ---- workspace layout (float indices) ----
#define OFF_WTT 0            // [6][64][64] f32 (WtT[k][c][d] = Wt_k[d][c])   len 24576
#define OFF_PK  24576        // packed f16 MLP weights, 34816 u16             len 17408
#define OFF_B2P 41984        // permuted bs2 f32 [192]                        len 192
#define OFF_IASH 42176       // [N][5][64] u32 packed fp16 pairs              len 3200000
#define OFF_EAH 3242176      // [E][3][64] f16 (ch' = comp*64+unit)           len 15360000
#define OFF_ATTRP 18602176   // [E][32] f16, bucket-ordered                   len 2560000
#define OFF_CP  21162176     // [E] f32 cutoff, bucket-ordered                len 160000
#define OFF_INT 21322176     // counts[N] cursor[N] offsets[N+1] dstp[E]

typedef __attribute__((ext_vector_type(8))) _Float16 h16x8;
typedef __attribute__((ext_vector_type(2))) __fp16 fp16x2_raw;
typedef __attribute__((ext_vector_type(4))) float f32x4;

__device__ __forceinline__ float silu_f(float x) {
    return x * __builtin_amdgcn_rcpf(1.0f + __expf(-x));
}
__device__ __forceinline__ unsigned int pkh(float a, float b) {
    union { fp16x2_raw h; unsigned int u; } cv;
    cv.h = __builtin_amdgcn_cvt_pkrtz(a, b);
    return cv.u;
}
__device__ __forceinline__ unsigned short f2h(float f) {
    union { _Float16 h; unsigned short u; } cv; cv.h = (_Float16)f; return cv.u;
}
__device__ __forceinline__ float h2f(unsigned short s) {
    union { unsigned short u; _Float16 h; } cv; cv.u = s; return (float)cv.h;
}
__device__ __forceinline__ float h2f_lo(unsigned int u) { return h2f((unsigned short)(u & 0xffffu)); }
__device__ __forceinline__ float h2f_hi(unsigned int u) { return h2f((unsigned short)(u >> 16)); }
__device__ __forceinline__ unsigned int bperm(int addr, unsigned int v) {
    return (unsigned int)__builtin_amdgcn_ds_bpermute(addr, (int)v);
}

// ---------------- prep: Wt transpose + f16 weight pack + bs2 permute + degree count ----------------
__global__ void k_prep(const float* __restrict__ Wt0, const float* __restrict__ Wt1,
                       const float* __restrict__ Wt2, const float* __restrict__ Wt3,
                       const float* __restrict__ Wt4, const float* __restrict__ Wt5,
                       const float* __restrict__ Ws0, const float* __restrict__ Ws1,
                       const float* __restrict__ Ws2, const float* __restrict__ bs2,
                       const int* __restrict__ ei,
                       float* __restrict__ WtT, unsigned short* __restrict__ PK,
                       float* __restrict__ bs2p, int* __restrict__ counts) {
    int idx = blockIdx.x * 256 + threadIdx.x;
    if (idx < 24576) {
        int k = idx >> 12, r = idx & 4095;
        int c = r >> 6, d = r & 63;
        const float* W = (k == 0) ? Wt0 : (k == 1) ? Wt1 : (k == 2) ? Wt2
                       : (k == 3) ? Wt3 : (k == 4) ? Wt4 : Wt5;
        WtT[idx] = W[d * 64 + c];
    } else if (idx < 26624) {            // P1: Ws0 [64 out][32 in]
        int q = idx - 24576;
        int ot = q >> 9, r = q & 511, lane = r >> 3, j = r & 7;
        int k = ((lane >> 4) * 8) + j, o = ot * 16 + (lane & 15);
        PK[q] = f2h(Ws0[o * 32 + k]);
    } else if (idx < 34816) {            // P2: Ws1 [128][64]
        int q = idx - 24576;
        int i = q - 2048, ch = i >> 9, r = i & 511, lane = r >> 3, j = r & 7;
        int ot = ch >> 1, ks = ch & 1;
        int k = ks * 32 + (lane >> 4) * 8 + j, o = ot * 16 + (lane & 15);
        PK[q] = f2h(Ws1[o * 64 + k]);
    } else if (idx < 59392) {            // P3: Ws2 [192][128], rows permuted ch'=comp*64+unit
        int q = idx - 24576;
        int i = q - 10240, ch = i >> 9, r = i & 511, lane = r >> 3, j = r & 7;
        int ot = ch >> 2, ks = ch & 3;
        int k = ks * 32 + (lane >> 4) * 8 + j;
        int op = ot * 16 + (lane & 15);
        int o = (op & 63) * 3 + (op >> 6);
        PK[q] = f2h(Ws2[o * 128 + k]);
    } else if (idx < 59584) {
        int op = idx - 59392;
        bs2p[op] = bs2[(op & 63) * 3 + (op >> 6)];
    } else if (idx < 59584 + EE) {
        int e = idx - 59584;
        atomicAdd(&counts[ei[e]], 1);
    }
}

// ---------------- CSR scan ----------------
__global__ __launch_bounds__(256) void k_scan(const int* __restrict__ counts,
                                              int* __restrict__ offsets) {
    __shared__ int sums[256];
    int t = threadIdx.x;
    int base = t * 40;
    int s = 0;
    if (base < NN) {
        const int4* p = (const int4*)(counts + base);
#pragma unroll
        for (int q = 0; q < 10; ++q) { int4 a = p[q]; s += a.x + a.y + a.z + a.w; }
    }
    sums[t] = s;
    __syncthreads();
    for (int off = 1; off < 256; off <<= 1) {
        int tmp = (t >= off) ? sums[t - off] : 0;
        __syncthreads();
        sums[t] += tmp;
        __syncthreads();
    }
    int run = sums[t] - s;
    if (base < NN) {
        const int4* p = (const int4*)(counts + base);
#pragma unroll
        for (int q = 0; q < 10; ++q) {
            int4 a = p[q];
            offsets[base + 4 * q + 0] = run; run += a.x;
            offsets[base + 4 * q + 1] = run; run += a.y;
            offsets[base + 4 * q + 2] = run; run += a.z;
            offsets[base + 4 * q + 3] = run; run += a.w;
        }
    }
    if (t == 255) offsets[NN] = run;
}

// ---------------- CSR fill + attr pre-gather (fp16) + cutoff precompute ----------------
__global__ void k_fill(const int* __restrict__ ei, const int* __restrict__ offsets,
                       const float* __restrict__ attr, const float* __restrict__ ew,
                       int* __restrict__ cursor, int* __restrict__ dstp,
                       unsigned short* __restrict__ attrP, float* __restrict__ Cp) {
    int e = blockIdx.x * 256 + threadIdx.x;
    if (e < EE) {
        int s = ei[e];
        int pos = offsets[s] + atomicAdd(&cursor[s], 1);
        dstp[pos] = ei[EE + e];
        const float4* ap = (const float4*)(attr + (size_t)e * 32);
        unsigned int pk[16];
#pragma unroll
        for (int q = 0; q < 8; ++q) {
            float4 v = ap[q];
            pk[2 * q]     = pkh(v.x, v.y);
            pk[2 * q + 1] = pkh(v.z, v.w);
        }
        uint4* dst = (uint4*)(attrP + (size_t)pos * 32);
#pragma unroll
        for (int q = 0; q < 4; ++q)
            dst[q] = make_uint4(pk[4 * q], pk[4 * q + 1], pk[4 * q + 2], pk[4 * q + 3]);
        float rw = ew[e];
        Cp[pos] = (rw < 1.0f) ? 0.5f * (cosf(3.14159265358979f * rw) + 1.0f) : 0.0f;
    }
}

// ---------------- combo: bpermute edge MLP (blocks < EE/64) + node prep (rest) ----------------
__global__ __launch_bounds__(256) void k_mlpnp(const unsigned short* __restrict__ attrP,
                                               const float* __restrict__ Cp,
                                               const unsigned short* __restrict__ PK,
                                               const float* __restrict__ bs0,
                                               const float* __restrict__ bs1,
                                               const float* __restrict__ bs2p,
                                               const float* __restrict__ X,
                                               const float* __restrict__ WtT,
                                               unsigned short* __restrict__ eah,
                                               unsigned int* __restrict__ IASu) {
    __shared__ float SH[4][1344];   // nodeprep branch: XS 576 + L 768 per wave
    int t = threadIdx.x, w = t >> 6, l = t & 63;
    if (blockIdx.x < EE / 64) {
        // ===== edge MLP: 16 edges/wave, no LDS, bpermute inter-layer transpose =====
        int e = l & 15, lg = l >> 4;
        int pos = blockIdx.x * 64 + w * 16 + e;
        const h16x8* P1 = (const h16x8*)PK;
        const h16x8* P2 = (const h16x8*)(PK + 2048);
        const h16x8* P3 = (const h16x8*)(PK + 10240);
        union U8 { h16x8 h; unsigned int u[4]; uint4 v; };
        U8 B1;
        B1.v = *((const uint4*)(attrP + (size_t)pos * 32) + lg);
        float C = Cp[pos];
        int src0 = ((lg & 1) * 32 + e) * 4;
        int src1 = src0 + 64;
        bool hi = (lg >= 2);

        unsigned int h01[8], h23[8];
#pragma unroll
        for (int ot = 0; ot < 4; ++ot) {
            float4 bb = *(const float4*)&bs0[ot * 16 + lg * 4];
            f32x4 acc = {bb.x, bb.y, bb.z, bb.w};
            acc = __builtin_amdgcn_mfma_f32_16x16x32_f16(P1[ot * 64 + l], B1.h, acc, 0, 0, 0);
            h01[ot] = pkh(silu_f(acc[0]), silu_f(acc[1]));
            h23[ot] = pkh(silu_f(acc[2]), silu_f(acc[3]));
        }
        U8 B2a, B2b;
        {
            unsigned int a, b;
            a = bperm(src0, h01[0]); b = bperm(src0, h01[1]); B2a.u[0] = hi ? b : a;
            a = bperm(src0, h23[0]); b = bperm(src0, h23[1]); B2a.u[1] = hi ? b : a;
            a = bperm(src1, h01[0]); b = bperm(src1, h01[1]); B2a.u[2] = hi ? b : a;
            a = bperm(src1, h23[0]); b = bperm(src1, h23[1]); B2a.u[3] = hi ? b : a;
            a = bperm(src0, h01[2]); b = bperm(src0, h01[3]); B2b.u[0] = hi ? b : a;
            a = bperm(src0, h23[2]); b = bperm(src0, h23[3]); B2b.u[1] = hi ? b : a;
            a = bperm(src1, h01[2]); b = bperm(src1, h01[3]); B2b.u[2] = hi ? b : a;
            a = bperm(src1, h23[2]); b = bperm(src1, h23[3]); B2b.u[3] = hi ? b : a;
        }
#pragma unroll
        for (int ot = 0; ot < 8; ++ot) {
            float4 bb = *(const float4*)&bs1[ot * 16 + lg * 4];
            f32x4 acc = {bb.x, bb.y, bb.z, bb.w};
            acc = __builtin_amdgcn_mfma_f32_16x16x32_f16(P2[(ot * 2 + 0) * 64 + l], B2a.h, acc, 0, 0, 0);
            acc = __builtin_amdgcn_mfma_f32_16x16x32_f16(P2[(ot * 2 + 1) * 64 + l], B2b.h, acc, 0, 0, 0);
            h01[ot] = pkh(silu_f(acc[0]), silu_f(acc[1]));
            h23[ot] = pkh(silu_f(acc[2]), silu_f(acc[3]));
        }
        U8 B3[4];
#pragma unroll
        for (int ks = 0; ks < 4; ++ks) {
            unsigned int a, b;
            a = bperm(src0, h01[ks * 2]); b = bperm(src0, h01[ks * 2 + 1]); B3[ks].u[0] = hi ? b : a;
            a = bperm(src0, h23[ks * 2]); b = bperm(src0, h23[ks * 2 + 1]); B3[ks].u[1] = hi ? b : a;
            a = bperm(src1, h01[ks * 2]); b = bperm(src1, h01[ks * 2 + 1]); B3[ks].u[2] = hi ? b : a;
            a = bperm(src1, h23[ks * 2]); b = bperm(src1, h23[ks * 2 + 1]); B3[ks].u[3] = hi ? b : a;
        }
        size_t ebase = (size_t)pos * 192;
#pragma unroll
        for (int ot = 0; ot < 12; ++ot) {
            float4 bb = *(const float4*)&bs2p[ot * 16 + lg * 4];
            f32x4 acc = {bb.x, bb.y, bb.z, bb.w};
            acc = __builtin_amdgcn_mfma_f32_16x16x32_f16(P3[(ot * 4 + 0) * 64 + l], B3[0].h, acc, 0, 0, 0);
            acc = __builtin_amdgcn_mfma_f32_16x16x32_f16(P3[(ot * 4 + 1) * 64 + l], B3[1].h, acc, 0, 0, 0);
            acc = __builtin_amdgcn_mfma_f32_16x16x32_f16(P3[(ot * 4 + 2) * 64 + l], B3[2].h, acc, 0, 0, 0);
            acc = __builtin_amdgcn_mfma_f32_16x16x32_f16(P3[(ot * 4 + 3) * 64 + l], B3[3].h, acc, 0, 0, 0);
            unsigned int u01 = pkh(silu_f(acc[0]) * C, silu_f(acc[1]) * C);
            unsigned int u23 = pkh(silu_f(acc[2]) * C, silu_f(acc[3]) * C);
            *(uint2*)&eah[ebase + ot * 16 + lg * 4] = make_uint2(u01, u23);
        }
    } else {
        // ===== node prep: 1 wave/node =====
        int c = l;
        int n = (blockIdx.x - EE / 64) * 4 + w;
        float* xs = SH[w];
        float (*L12)[12] = (float (*)[12])(xs + 576);
#pragma unroll
        for (int i = 0; i < 9; i++) xs[c + 64 * i] = X[(size_t)n * 576 + c + 64 * i];
        __builtin_amdgcn_wave_barrier();
        float x[9];
#pragma unroll
        for (int j = 0; j < 9; j++) x[j] = xs[c * 9 + j];
        float nrm = 0.f;
#pragma unroll
        for (int j = 0; j < 9; j++) nrm += x[j] * x[j];
        float inv = __builtin_amdgcn_rcpf(nrm + 1.0f);
#pragma unroll
        for (int j = 0; j < 9; j++) x[j] *= inv;
        float tr3 = (x[0] + x[4] + x[8]) * (1.0f / 3.0f);
        L12[c][0] = tr3;
        L12[c][1] = 0.5f * (x[1] - x[3]);
        L12[c][2] = 0.5f * (x[2] - x[6]);
        L12[c][3] = 0.5f * (x[5] - x[7]);
        L12[c][4] = x[0] - tr3;
        L12[c][5] = x[4] - tr3;
        L12[c][6] = 0.5f * (x[1] + x[3]);
        L12[c][7] = 0.5f * (x[2] + x[6]);
        L12[c][8] = 0.5f * (x[5] + x[7]);
        __builtin_amdgcn_wave_barrier();
        int d = c;
        const float* W0 = WtT;
        const float* W1 = WtT + 4096;
        const float* W2 = WtT + 8192;
        float aI = 0, aA0 = 0, aA1 = 0, aA2 = 0, aS0 = 0, aS1 = 0, aS2 = 0, aS3 = 0, aS4 = 0;
        for (int cc = 0; cc < 64; ++cc) {
            float w0 = W0[cc * 64 + d], w1 = W1[cc * 64 + d], w2 = W2[cc * 64 + d];
            float4 L0 = *(const float4*)&L12[cc][0];
            float4 L1 = *(const float4*)&L12[cc][4];
            float L8 = L12[cc][8];
            aI  += w0 * L0.x;
            aA0 += w1 * L0.y; aA1 += w1 * L0.z; aA2 += w1 * L0.w;
            aS0 += w2 * L1.x; aS1 += w2 * L1.y; aS2 += w2 * L1.z;
            aS3 += w2 * L1.w; aS4 += w2 * L8;
        }
        unsigned int* op = IASu + (size_t)n * 320 + d;
        op[0]   = pkh(aI, aA0);
        op[64]  = pkh(aA1, aA2);
        op[128] = pkh(aS0, aS1);
        op[192] = pkh(aS2, aS3);
        op[256] = pkh(aS4, 0.0f);
    }
}

// ---------------- fused aggregation + output: 4 nodes/block, 1 wave/node ----------------
// dstp preloaded per-lane + __shfl broadcast removes the dependent dstp->IAS chain.
__global__ __launch_bounds__(256) void k_aggout(const int* __restrict__ offsets,
                                                const int* __restrict__ dstp,
                                                const unsigned short* __restrict__ eah,
                                                const unsigned int* __restrict__ IASu,
                                                const float* __restrict__ X,
                                                const float* __restrict__ WtT,
                                                float* __restrict__ out) {
    int t = threadIdx.x, w = t >> 6, c = t & 63;
    int n = blockIdx.x * 4 + w;
    __shared__ float XS[4][576];
    __shared__ float LO[4][768];
    float* xs = XS[w];
    float* lo = LO[w];
#pragma unroll
    for (int i = 0; i < 9; i++) xs[c + 64 * i] = X[(size_t)n * 576 + c + 64 * i];

    int beg = offsets[n], end = offsets[n + 1];
    int dv = 0;
    { int idx = beg + c; if (idx < end) dv = dstp[idx]; }
    float m0 = 0, m1 = 0, m2 = 0, m3 = 0, m4 = 0, m5 = 0, m6 = 0, m7 = 0, m8 = 0;
    int i = beg;
    for (; i + 4 <= end; i += 4) {
        int q0 = i - beg;
        int d0 = (q0 < 64)     ? __shfl(dv, q0)     : dstp[i];
        int d1 = (q0 + 1 < 64) ? __shfl(dv, q0 + 1) : dstp[i + 1];
        int d2 = (q0 + 2 < 64) ? __shfl(dv, q0 + 2) : dstp[i + 2];
        int d3 = (q0 + 3 < 64) ? __shfl(dv, q0 + 3) : dstp[i + 3];
        int dd[4] = {d0, d1, d2, d3};
        float a[4][3];
        unsigned int u[4][5];
#pragma unroll
        for (int q = 0; q < 4; ++q) {
            const unsigned short* ep = eah + (size_t)(i + q) * 192;
            a[q][0] = h2f(ep[c]); a[q][1] = h2f(ep[64 + c]); a[q][2] = h2f(ep[128 + c]);
            const unsigned int* p = IASu + (size_t)dd[q] * 320 + c;
            u[q][0] = p[0]; u[q][1] = p[64]; u[q][2] = p[128]; u[q][3] = p[192]; u[q][4] = p[256];
        }
#pragma unroll
        for (int q = 0; q < 4; ++q) {
            m0 += a[q][0] * h2f_lo(u[q][0]); m1 += a[q][1] * h2f_hi(u[q][0]);
            m2 += a[q][1] * h2f_lo(u[q][1]); m3 += a[q][1] * h2f_hi(u[q][1]);
            m4 += a[q][2] * h2f_lo(u[q][2]); m5 += a[q][2] * h2f_hi(u[q][2]);
            m6 += a[q][2] * h2f_lo(u[q][3]); m7 += a[q][2] * h2f_hi(u[q][3]);
            m8 += a[q][2] * h2f_lo(u[q][4]);
        }
    }
    for (; i < end; ++i) {
        int q0 = i - beg;
        int dst = (q0 < 64) ? __shfl(dv, q0) : dstp[i];
        const unsigned short* ep = eah + (size_t)i * 192;
        float a0 = h2f(ep[c]), a1 = h2f(ep[64 + c]), a2 = h2f(ep[128 + c]);
        const unsigned int* p = IASu + (size_t)dst * 320 + c;
        unsigned int u0 = p[0], u1 = p[64], u2 = p[128], u3 = p[192], u4 = p[256];
        m0 += a0 * h2f_lo(u0); m1 += a1 * h2f_hi(u0);
        m2 += a1 * h2f_lo(u1); m3 += a1 * h2f_hi(u1);
        m4 += a2 * h2f_lo(u2); m5 += a2 * h2f_hi(u2);
        m6 += a2 * h2f_lo(u3); m7 += a2 * h2f_hi(u3);
        m8 += a2 * h2f_lo(u4);
    }
    const unsigned int* yp = IASu + (size_t)n * 320 + c;
    unsigned int y0 = yp[0], y1 = yp[64], y2 = yp[128], y3 = yp[192], y4 = yp[256];
    float yI = h2f_lo(y0), yA0 = h2f_hi(y0), yA1 = h2f_lo(y1), yA2 = h2f_hi(y1);
    float yS0 = h2f_lo(y2), yS1 = h2f_hi(y2), yS2 = h2f_lo(y3), yS3 = h2f_hi(y3);
    float yS4 = h2f_lo(y4);

    float M[3][3] = {
        { m0 + m4,   m1 + m6,  m2 + m7 },
        { -m1 + m6,  m0 + m5,  m3 + m8 },
        { -m2 + m7, -m3 + m8,  m0 - m4 - m5 } };
    float Y[3][3] = {
        { yI + yS0,   yA0 + yS2,  yA1 + yS3 },
        { -yA0 + yS2, yI + yS1,   yA2 + yS4 },
        { -yA1 + yS3, -yA2 + yS4, yI - yS0 - yS1 } };
    float AB[3][3];
#pragma unroll
    for (int ii = 0; ii < 3; ii++)
#pragma unroll
        for (int j = 0; j < 3; j++) {
            float s = 0.f;
#pragma unroll
            for (int k = 0; k < 3; k++) s += M[ii][k] * Y[k][j] + Y[ii][k] * M[k][j];
            AB[ii][j] = s;
        }
    float tr3 = (AB[0][0] + AB[1][1] + AB[2][2]) * (1.0f / 3.0f);
    float fro = 0.f;
#pragma unroll
    for (int ii = 0; ii < 3; ii++)
#pragma unroll
        for (int j = 0; j < 3; j++) fro += AB[ii][j] * AB[ii][j];
    float inv = __builtin_amdgcn_rcpf(fro + 1.0f);
    float (*L12)[12] = (float (*)[12])lo;
    L12[c][0] = tr3 * inv;
    L12[c][1] = 0.5f * (AB[0][1] - AB[1][0]) * inv;
    L12[c][2] = 0.5f * (AB[0][2] - AB[2][0]) * inv;
    L12[c][3] = 0.5f * (AB[1][2] - AB[2][1]) * inv;
    L12[c][4] = (AB[0][0] - tr3) * inv;
    L12[c][5] = (AB[1][1] - tr3) * inv;
    L12[c][6] = 0.5f * (AB[0][1] + AB[1][0]) * inv;
    L12[c][7] = 0.5f * (AB[0][2] + AB[2][0]) * inv;
    L12[c][8] = 0.5f * (AB[1][2] + AB[2][1]) * inv;
    __builtin_amdgcn_wave_barrier();
    int d = c;
    const float* W3 = WtT + 3 * 4096;
    const float* W4 = WtT + 4 * 4096;
    const float* W5 = WtT + 5 * 4096;
    float aI = 0, aA0 = 0, aA1 = 0, aA2 = 0, aS0 = 0, aS1 = 0, aS2 = 0, aS3 = 0, aS4 = 0;
    for (int cc = 0; cc < 64; ++cc) {
        float w3 = W3[cc * 64 + d], w4 = W4[cc * 64 + d], w5 = W5[cc * 64 + d];
        float4 L0 = *(const float4*)&L12[cc][0];
        float4 L1 = *(const float4*)&L12[cc][4];
        float L8 = L12[cc][8];
        aI  += w3 * L0.x;
        aA0 += w4 * L0.y; aA1 += w4 * L0.z; aA2 += w4 * L0.w;
        aS0 += w5 * L1.x; aS1 += w5 * L1.y; aS2 += w5 * L1.z;
        aS3 += w5 * L1.w; aS4 += w5 * L8;
    }
    float dX[3][3] = {
        { aI + aS0,   aA0 + aS2,  aA1 + aS3 },
        { -aA0 + aS2, aI + aS1,   aA2 + aS4 },
        { -aA1 + aS3, -aA2 + aS4, aI - aS0 - aS1 } };
    float D2[3][3];
#pragma unroll
    for (int ii = 0; ii < 3; ii++)
#pragma unroll
        for (int j = 0; j < 3; j++) {
            float s = 0.f;
#pragma unroll
            for (int k = 0; k < 3; k++) s += dX[ii][k] * dX[k][j];
            D2[ii][j] = s;
        }
    float x[9];
    __builtin_amdgcn_wave_barrier();
#pragma unroll
    for (int j = 0; j < 9; j++) x[j] = xs[d * 9 + j];
    float nrm = 0.f;
#pragma unroll
    for (int j = 0; j < 9; j++) nrm += x[j] * x[j];
    float xinv = __builtin_amdgcn_rcpf(nrm + 1.0f);
    __builtin_amdgcn_wave_barrier();
#pragma unroll
    for (int ii = 0; ii < 3; ii++)
#pragma unroll
        for (int j = 0; j < 3; j++)
            lo[d * 9 + ii * 3 + j] = x[ii * 3 + j] * xinv + dX[ii][j] + D2[ii][j];
    __builtin_amdgcn_wave_barrier();
#pragma unroll
    for (int ii = 0; ii < 9; ii++) out[(size_t)n * 576 + c + 64 * ii] = lo[c + 64 * ii];
}

extern "C" void kernel_launch(void* const* d_in, const int* in_sizes, int n_in,
                              void* d_out, int out_size, void* d_ws, size_t ws_size,
                              hipStream_t stream) {
    (void)in_sizes; (void)n_in; (void)out_size; (void)ws_size;
    const int* ei = (const int*)d_in[0];
    const float* ew = (const float*)d_in[1];
    const float* attr = (const float*)d_in[2];
    const float* X = (const float*)d_in[3];
    const float* Ws0 = (const float*)d_in[4];
    const float* bs0 = (const float*)d_in[5];
    const float* Ws1 = (const float*)d_in[6];
    const float* bs1 = (const float*)d_in[7];
    const float* Ws2 = (const float*)d_in[8];
    const float* bs2 = (const float*)d_in[9];
    const float* Wt0 = (const float*)d_in[10];
    const float* Wt1 = (const float*)d_in[11];
    const float* Wt2 = (const float*)d_in[12];
    const float* Wt3 = (const float*)d_in[13];
    const float* Wt4 = (const float*)d_in[14];
    const float* Wt5 = (const float*)d_in[15];
    float* ws = (float*)d_ws;
    int* ibase = (int*)(ws + OFF_INT);
    int* counts = ibase;
    int* cursor = ibase + NN;
    int* offsets = ibase + 2 * NN;
    int* dstp = ibase + 3 * NN + 1;
    unsigned short* PK = (unsigned short*)(ws + OFF_PK);
    unsigned int* IASu = (unsigned int*)(ws + OFF_IASH);
    unsigned short* eah = (unsigned short*)(ws + OFF_EAH);
    unsigned short* attrP = (unsigned short*)(ws + OFF_ATTRP);
    float* Cp = ws + OFF_CP;

    (void)hipMemsetAsync(counts, 0, 2 * NN * sizeof(int), stream);
    k_prep<<<(59584 + EE + 255) / 256, 256, 0, stream>>>(
        Wt0, Wt1, Wt2, Wt3, Wt4, Wt5, Ws0, Ws1, Ws2, bs2, ei,
        ws, PK, ws + OFF_B2P, counts);
    k_scan<<<1, 256, 0, stream>>>(counts, offsets);
    k_fill<<<(EE + 255) / 256, 256, 0, stream>>>(ei, offsets, attr, ew, cursor, dstp, attrP, Cp);
    k_mlpnp<<<EE / 64 + NN / 4, 256, 0, stream>>>(attrP, Cp, PK, bs0, bs1, ws + OFF_B2P,
                                                  X, ws, eah, IASu);
    k_aggout<<<NN / 4, 256, 0, stream>>>(offsets, dstp, eah, IASu, X, ws, (float*)d_out);
}

// Round 15
// 148.718 us; speedup vs baseline: 1.0886x; 1.0818x over previous
//
#include <hip/hip_runtime.h>
#include <math.h>

#define NN 10000
#define EE 160000

// ---- workspace layout (float indices) ----
#define OFF_WTT 0            // [6][64][64] f32 (WtT[k][c][d] = Wt_k[d][c])   len 24576
#define OFF_PK  24576        // packed f16 MLP weights, 34816 u16             len 17408
#define OFF_B2P 41984        // permuted bs2 f32 [192]                        len 192
#define OFF_IASH 42176       // [N][5][64] u32 packed fp16 pairs              len 3200000
#define OFF_EAH 3242176      // [E][3][64] f16 (ch' = comp*64+unit)           len 15360000
#define OFF_ATTRP 18602176   // [E][32] f16, bucket-ordered                   len 2560000
#define OFF_CP  21162176     // [E] f32 cutoff, bucket-ordered                len 160000
#define OFF_INT 21322176     // counts[N] cursor[N] offsets[N+1] dstp[E]

typedef __attribute__((ext_vector_type(8))) _Float16 h16x8;
typedef __attribute__((ext_vector_type(2))) __fp16 fp16x2_raw;
typedef __attribute__((ext_vector_type(4))) float f32x4;

__device__ __forceinline__ float silu_f(float x) {
    return x * __builtin_amdgcn_rcpf(1.0f + __expf(-x));
}
__device__ __forceinline__ unsigned int pkh(float a, float b) {
    union { fp16x2_raw h; unsigned int u; } cv;
    cv.h = __builtin_amdgcn_cvt_pkrtz(a, b);
    return cv.u;
}
__device__ __forceinline__ unsigned short f2h(float f) {
    union { _Float16 h; unsigned short u; } cv; cv.h = (_Float16)f; return cv.u;
}
__device__ __forceinline__ float h2f(unsigned short s) {
    union { unsigned short u; _Float16 h; } cv; cv.u = s; return (float)cv.h;
}
__device__ __forceinline__ float h2f_lo(unsigned int u) { return h2f((unsigned short)(u & 0xffffu)); }
__device__ __forceinline__ float h2f_hi(unsigned int u) { return h2f((unsigned short)(u >> 16)); }

// ---------------- prep: Wt transpose + f16 weight pack + bs2 permute + degree count ----------------
__global__ void k_prep(const float* __restrict__ Wt0, const float* __restrict__ Wt1,
                       const float* __restrict__ Wt2, const float* __restrict__ Wt3,
                       const float* __restrict__ Wt4, const float* __restrict__ Wt5,
                       const float* __restrict__ Ws0, const float* __restrict__ Ws1,
                       const float* __restrict__ Ws2, const float* __restrict__ bs2,
                       const int* __restrict__ ei,
                       float* __restrict__ WtT, unsigned short* __restrict__ PK,
                       float* __restrict__ bs2p, int* __restrict__ counts) {
    int idx = blockIdx.x * 256 + threadIdx.x;
    if (idx < 24576) {
        int k = idx >> 12, r = idx & 4095;
        int c = r >> 6, d = r & 63;
        const float* W = (k == 0) ? Wt0 : (k == 1) ? Wt1 : (k == 2) ? Wt2
                       : (k == 3) ? Wt3 : (k == 4) ? Wt4 : Wt5;
        WtT[idx] = W[d * 64 + c];
    } else if (idx < 26624) {            // P1: Ws0 [64 out][32 in]
        int q = idx - 24576;
        int ot = q >> 9, r = q & 511, lane = r >> 3, j = r & 7;
        int k = ((lane >> 4) * 8) + j, o = ot * 16 + (lane & 15);
        PK[q] = f2h(Ws0[o * 32 + k]);
    } else if (idx < 34816) {            // P2: Ws1 [128][64]
        int q = idx - 24576;
        int i = q - 2048, ch = i >> 9, r = i & 511, lane = r >> 3, j = r & 7;
        int ot = ch >> 1, ks = ch & 1;
        int k = ks * 32 + (lane >> 4) * 8 + j, o = ot * 16 + (lane & 15);
        PK[q] = f2h(Ws1[o * 64 + k]);
    } else if (idx < 59392) {            // P3: Ws2 [192][128], rows permuted ch'=comp*64+unit
        int q = idx - 24576;
        int i = q - 10240, ch = i >> 9, r = i & 511, lane = r >> 3, j = r & 7;
        int ot = ch >> 2, ks = ch & 3;
        int k = ks * 32 + (lane >> 4) * 8 + j;
        int op = ot * 16 + (lane & 15);
        int o = (op & 63) * 3 + (op >> 6);
        PK[q] = f2h(Ws2[o * 128 + k]);
    } else if (idx < 59584) {
        int op = idx - 59392;
        bs2p[op] = bs2[(op & 63) * 3 + (op >> 6)];
    } else if (idx < 59584 + EE) {
        int e = idx - 59584;
        atomicAdd(&counts[ei[e]], 1);
    }
}

// ---------------- CSR scan ----------------
__global__ __launch_bounds__(256) void k_scan(const int* __restrict__ counts,
                                              int* __restrict__ offsets) {
    __shared__ int sums[256];
    int t = threadIdx.x;
    int base = t * 40;
    int s = 0;
    if (base < NN) {
        const int4* p = (const int4*)(counts + base);
#pragma unroll
        for (int q = 0; q < 10; ++q) { int4 a = p[q]; s += a.x + a.y + a.z + a.w; }
    }
    sums[t] = s;
    __syncthreads();
    for (int off = 1; off < 256; off <<= 1) {
        int tmp = (t >= off) ? sums[t - off] : 0;
        __syncthreads();
        sums[t] += tmp;
        __syncthreads();
    }
    int run = sums[t] - s;
    if (base < NN) {
        const int4* p = (const int4*)(counts + base);
#pragma unroll
        for (int q = 0; q < 10; ++q) {
            int4 a = p[q];
            offsets[base + 4 * q + 0] = run; run += a.x;
            offsets[base + 4 * q + 1] = run; run += a.y;
            offsets[base + 4 * q + 2] = run; run += a.z;
            offsets[base + 4 * q + 3] = run; run += a.w;
        }
    }
    if (t == 255) offsets[NN] = run;
}

// ---------------- CSR fill + attr pre-gather (fp16) + cutoff precompute ----------------
__global__ void k_fill(const int* __restrict__ ei, const int* __restrict__ offsets,
                       const float* __restrict__ attr, const float* __restrict__ ew,
                       int* __restrict__ cursor, int* __restrict__ dstp,
                       unsigned short* __restrict__ attrP, float* __restrict__ Cp) {
    int e = blockIdx.x * 256 + threadIdx.x;
    if (e < EE) {
        int s = ei[e];
        int pos = offsets[s] + atomicAdd(&cursor[s], 1);
        dstp[pos] = ei[EE + e];
        const float4* ap = (const float4*)(attr + (size_t)e * 32);
        unsigned int pk[16];
#pragma unroll
        for (int q = 0; q < 8; ++q) {
            float4 v = ap[q];
            pk[2 * q]     = pkh(v.x, v.y);
            pk[2 * q + 1] = pkh(v.z, v.w);
        }
        uint4* dst = (uint4*)(attrP + (size_t)pos * 32);
#pragma unroll
        for (int q = 0; q < 4; ++q)
            dst[q] = make_uint4(pk[4 * q], pk[4 * q + 1], pk[4 * q + 2], pk[4 * q + 3]);
        float rw = ew[e];
        Cp[pos] = (rw < 1.0f) ? 0.5f * (cosf(3.14159265358979f * rw) + 1.0f) : 0.0f;
    }
}

// ---------------- combo: edge MLP (blocks < EE/128) + node prep (rest), co-scheduled ----------------
__global__ __launch_bounds__(256) void k_mlpnp(const unsigned short* __restrict__ attrP,
                                               const float* __restrict__ Cp,
                                               const unsigned short* __restrict__ PK,
                                               const float* __restrict__ bs0,
                                               const float* __restrict__ bs1,
                                               const float* __restrict__ bs2p,
                                               const float* __restrict__ X,
                                               const float* __restrict__ WtT,
                                               unsigned short* __restrict__ eah,
                                               unsigned int* __restrict__ IASu) {
    __shared__ unsigned short SH[4][4352];   // per-wave scratch (8704 B)
    int t = threadIdx.x, w = t >> 6, l = t & 63;
    if (blockIdx.x < EE / 128) {
        // ================= edge MLP: 32 edges/wave (2 tiles), all-fp16 inputs =================
        int lr = l & 15, lg = l >> 4;
        int base = blockIdx.x * 128 + w * 32;
        unsigned short* Hh = SH[w];          // [2][16][136]
        const h16x8* P1 = (const h16x8*)PK;
        const h16x8* P2 = (const h16x8*)(PK + 2048);
        const h16x8* P3 = (const h16x8*)(PK + 10240);
        union { h16x8 h; uint4 v; } B1[2];
        float C[2];
#pragma unroll
        for (int tt = 0; tt < 2; ++tt) {
            int p = base + tt * 16 + lr;
            B1[tt].v = *((const uint4*)(attrP + (size_t)p * 32) + lg);
            C[tt] = Cp[p];
        }
        // layer 1: 32 -> 64
#pragma unroll
        for (int ot = 0; ot < 4; ++ot) {
            h16x8 wf = P1[ot * 64 + l];
            float4 bb = *(const float4*)&bs0[ot * 16 + lg * 4];
#pragma unroll
            for (int tt = 0; tt < 2; ++tt) {
                f32x4 acc = {bb.x, bb.y, bb.z, bb.w};
                acc = __builtin_amdgcn_mfma_f32_16x16x32_f16(wf, B1[tt].h, acc, 0, 0, 0);
                unsigned int u01 = pkh(silu_f(acc[0]), silu_f(acc[1]));
                unsigned int u23 = pkh(silu_f(acc[2]), silu_f(acc[3]));
                *(uint2*)&Hh[tt * 2176 + lr * 136 + ot * 16 + lg * 4] = make_uint2(u01, u23);
            }
        }
        __builtin_amdgcn_wave_barrier();
        // layer 2: 64 -> 128
        h16x8 B2a[2], B2b[2];
#pragma unroll
        for (int tt = 0; tt < 2; ++tt) {
            B2a[tt] = *(const h16x8*)&Hh[tt * 2176 + lr * 136 + lg * 8];
            B2b[tt] = *(const h16x8*)&Hh[tt * 2176 + lr * 136 + 32 + lg * 8];
        }
        __builtin_amdgcn_wave_barrier();
#pragma unroll
        for (int ot = 0; ot < 8; ++ot) {
            h16x8 wf0 = P2[(ot * 2 + 0) * 64 + l];
            h16x8 wf1 = P2[(ot * 2 + 1) * 64 + l];
            float4 bb = *(const float4*)&bs1[ot * 16 + lg * 4];
#pragma unroll
            for (int tt = 0; tt < 2; ++tt) {
                f32x4 acc = {bb.x, bb.y, bb.z, bb.w};
                acc = __builtin_amdgcn_mfma_f32_16x16x32_f16(wf0, B2a[tt], acc, 0, 0, 0);
                acc = __builtin_amdgcn_mfma_f32_16x16x32_f16(wf1, B2b[tt], acc, 0, 0, 0);
                unsigned int u01 = pkh(silu_f(acc[0]), silu_f(acc[1]));
                unsigned int u23 = pkh(silu_f(acc[2]), silu_f(acc[3]));
                *(uint2*)&Hh[tt * 2176 + lr * 136 + ot * 16 + lg * 4] = make_uint2(u01, u23);
            }
        }
        __builtin_amdgcn_wave_barrier();
        // layer 3: 128 -> 192 (permuted channels), scale by C
        h16x8 B3[4][2];
#pragma unroll
        for (int ks = 0; ks < 4; ++ks)
#pragma unroll
            for (int tt = 0; tt < 2; ++tt)
                B3[ks][tt] = *(const h16x8*)&Hh[tt * 2176 + lr * 136 + ks * 32 + lg * 8];
#pragma unroll
        for (int ot = 0; ot < 12; ++ot) {
            h16x8 wf0 = P3[(ot * 4 + 0) * 64 + l];
            h16x8 wf1 = P3[(ot * 4 + 1) * 64 + l];
            h16x8 wf2 = P3[(ot * 4 + 2) * 64 + l];
            h16x8 wf3 = P3[(ot * 4 + 3) * 64 + l];
            float4 bb = *(const float4*)&bs2p[ot * 16 + lg * 4];
#pragma unroll
            for (int tt = 0; tt < 2; ++tt) {
                f32x4 acc = {bb.x, bb.y, bb.z, bb.w};
                acc = __builtin_amdgcn_mfma_f32_16x16x32_f16(wf0, B3[0][tt], acc, 0, 0, 0);
                acc = __builtin_amdgcn_mfma_f32_16x16x32_f16(wf1, B3[1][tt], acc, 0, 0, 0);
                acc = __builtin_amdgcn_mfma_f32_16x16x32_f16(wf2, B3[2][tt], acc, 0, 0, 0);
                acc = __builtin_amdgcn_mfma_f32_16x16x32_f16(wf3, B3[3][tt], acc, 0, 0, 0);
                unsigned int u01 = pkh(silu_f(acc[0]) * C[tt], silu_f(acc[1]) * C[tt]);
                unsigned int u23 = pkh(silu_f(acc[2]) * C[tt], silu_f(acc[3]) * C[tt]);
                *(uint2*)&eah[(size_t)(base + tt * 16 + lr) * 192 + ot * 16 + lg * 4]
                    = make_uint2(u01, u23);
            }
        }
    } else {
        // ================= node prep: 1 wave/node =================
        int c = l;
        int n = (blockIdx.x - EE / 128) * 4 + w;
        float* xs = (float*)SH[w];           // 576 f32
        float (*L12)[12] = (float (*)[12])(xs + 576);   // 768 f32
#pragma unroll
        for (int i = 0; i < 9; i++) xs[c + 64 * i] = X[(size_t)n * 576 + c + 64 * i];
        __builtin_amdgcn_wave_barrier();
        float x[9];
#pragma unroll
        for (int j = 0; j < 9; j++) x[j] = xs[c * 9 + j];
        float nrm = 0.f;
#pragma unroll
        for (int j = 0; j < 9; j++) nrm += x[j] * x[j];
        float inv = __builtin_amdgcn_rcpf(nrm + 1.0f);
#pragma unroll
        for (int j = 0; j < 9; j++) x[j] *= inv;
        float tr3 = (x[0] + x[4] + x[8]) * (1.0f / 3.0f);
        L12[c][0] = tr3;
        L12[c][1] = 0.5f * (x[1] - x[3]);
        L12[c][2] = 0.5f * (x[2] - x[6]);
        L12[c][3] = 0.5f * (x[5] - x[7]);
        L12[c][4] = x[0] - tr3;
        L12[c][5] = x[4] - tr3;
        L12[c][6] = 0.5f * (x[1] + x[3]);
        L12[c][7] = 0.5f * (x[2] + x[6]);
        L12[c][8] = 0.5f * (x[5] + x[7]);
        __builtin_amdgcn_wave_barrier();
        int d = c;
        const float* W0 = WtT;
        const float* W1 = WtT + 4096;
        const float* W2 = WtT + 8192;
        float aI = 0, aA0 = 0, aA1 = 0, aA2 = 0, aS0 = 0, aS1 = 0, aS2 = 0, aS3 = 0, aS4 = 0;
        for (int cc = 0; cc < 64; ++cc) {
            float w0 = W0[cc * 64 + d], w1 = W1[cc * 64 + d], w2 = W2[cc * 64 + d];
            float4 L0 = *(const float4*)&L12[cc][0];
            float4 L1 = *(const float4*)&L12[cc][4];
            float L8 = L12[cc][8];
            aI  += w0 * L0.x;
            aA0 += w1 * L0.y; aA1 += w1 * L0.z; aA2 += w1 * L0.w;
            aS0 += w2 * L1.x; aS1 += w2 * L1.y; aS2 += w2 * L1.z;
            aS3 += w2 * L1.w; aS4 += w2 * L8;
        }
        unsigned int* op = IASu + (size_t)n * 320 + d;
        op[0]   = pkh(aI, aA0);
        op[64]  = pkh(aA1, aA2);
        op[128] = pkh(aS0, aS1);
        op[192] = pkh(aS2, aS3);
        op[256] = pkh(aS4, 0.0f);
    }
}

// ---------------- fused aggregation + output: 2 nodes/block, 2 waves/node ----------------
__global__ __launch_bounds__(256) void k_aggout(const int* __restrict__ offsets,
                                                const int* __restrict__ dstp,
                                                const unsigned short* __restrict__ eah,
                                                const unsigned int* __restrict__ IASu,
                                                const float* __restrict__ X,
                                                const float* __restrict__ WtT,
                                                float* __restrict__ out) {
    int t = threadIdx.x, w = t >> 6, c = t & 63;
    int nw = w >> 1, half = w & 1;
    int n = blockIdx.x * 2 + nw;
    __shared__ float PS[2][9][64];
    __shared__ float XS[2][576];
    __shared__ float LO[2][768];
    float* xs = XS[nw];
    float* lo = LO[nw];
    // X staging split across the wave pair
    if (half == 0) {
#pragma unroll
        for (int i = 0; i < 5; i++) xs[c + 64 * i] = X[(size_t)n * 576 + c + 64 * i];
    } else {
#pragma unroll
        for (int i = 5; i < 9; i++) xs[c + 64 * i] = X[(size_t)n * 576 + c + 64 * i];
    }

    int beg = offsets[n], end = offsets[n + 1];
    int deg = end - beg;
    int mid = beg + (((deg / 2) + 3) & ~3);
    if (mid > end) mid = end;
    int i0 = half ? mid : beg;
    int i1 = half ? end : mid;

    float m0 = 0, m1 = 0, m2 = 0, m3 = 0, m4 = 0, m5 = 0, m6 = 0, m7 = 0, m8 = 0;
    int i = i0;
    for (; i + 4 <= i1; i += 4) {
        float a[4][3];
        unsigned int u[4][5];
#pragma unroll
        for (int q = 0; q < 4; ++q) {
            const unsigned short* ep = eah + (size_t)(i + q) * 192;
            a[q][0] = h2f(ep[c]); a[q][1] = h2f(ep[64 + c]); a[q][2] = h2f(ep[128 + c]);
            const unsigned int* p = IASu + (size_t)dstp[i + q] * 320 + c;
            u[q][0] = p[0]; u[q][1] = p[64]; u[q][2] = p[128]; u[q][3] = p[192]; u[q][4] = p[256];
        }
#pragma unroll
        for (int q = 0; q < 4; ++q) {
            m0 += a[q][0] * h2f_lo(u[q][0]); m1 += a[q][1] * h2f_hi(u[q][0]);
            m2 += a[q][1] * h2f_lo(u[q][1]); m3 += a[q][1] * h2f_hi(u[q][1]);
            m4 += a[q][2] * h2f_lo(u[q][2]); m5 += a[q][2] * h2f_hi(u[q][2]);
            m6 += a[q][2] * h2f_lo(u[q][3]); m7 += a[q][2] * h2f_hi(u[q][3]);
            m8 += a[q][2] * h2f_lo(u[q][4]);
        }
    }
    for (; i < i1; ++i) {
        const unsigned short* ep = eah + (size_t)i * 192;
        float a0 = h2f(ep[c]), a1 = h2f(ep[64 + c]), a2 = h2f(ep[128 + c]);
        const unsigned int* p = IASu + (size_t)dstp[i] * 320 + c;
        unsigned int u0 = p[0], u1 = p[64], u2 = p[128], u3 = p[192], u4 = p[256];
        m0 += a0 * h2f_lo(u0); m1 += a1 * h2f_hi(u0);
        m2 += a1 * h2f_lo(u1); m3 += a1 * h2f_hi(u1);
        m4 += a2 * h2f_lo(u2); m5 += a2 * h2f_hi(u2);
        m6 += a2 * h2f_lo(u3); m7 += a2 * h2f_hi(u3);
        m8 += a2 * h2f_lo(u4);
    }
    if (half == 1) {
        PS[nw][0][c] = m0; PS[nw][1][c] = m1; PS[nw][2][c] = m2;
        PS[nw][3][c] = m3; PS[nw][4][c] = m4; PS[nw][5][c] = m5;
        PS[nw][6][c] = m6; PS[nw][7][c] = m7; PS[nw][8][c] = m8;
    }
    __syncthreads();
    if (half == 1) return;
    m0 += PS[nw][0][c]; m1 += PS[nw][1][c]; m2 += PS[nw][2][c];
    m3 += PS[nw][3][c]; m4 += PS[nw][4][c]; m5 += PS[nw][5][c];
    m6 += PS[nw][6][c]; m7 += PS[nw][7][c]; m8 += PS[nw][8][c];

    const unsigned int* yp = IASu + (size_t)n * 320 + c;
    unsigned int y0 = yp[0], y1 = yp[64], y2 = yp[128], y3 = yp[192], y4 = yp[256];
    float yI = h2f_lo(y0), yA0 = h2f_hi(y0), yA1 = h2f_lo(y1), yA2 = h2f_hi(y1);
    float yS0 = h2f_lo(y2), yS1 = h2f_hi(y2), yS2 = h2f_lo(y3), yS3 = h2f_hi(y3);
    float yS4 = h2f_lo(y4);

    float M[3][3] = {
        { m0 + m4,   m1 + m6,  m2 + m7 },
        { -m1 + m6,  m0 + m5,  m3 + m8 },
        { -m2 + m7, -m3 + m8,  m0 - m4 - m5 } };
    float Y[3][3] = {
        { yI + yS0,   yA0 + yS2,  yA1 + yS3 },
        { -yA0 + yS2, yI + yS1,   yA2 + yS4 },
        { -yA1 + yS3, -yA2 + yS4, yI - yS0 - yS1 } };
    float AB[3][3];
#pragma unroll
    for (int ii = 0; ii < 3; ii++)
#pragma unroll
        for (int j = 0; j < 3; j++) {
            float s = 0.f;
#pragma unroll
            for (int k = 0; k < 3; k++) s += M[ii][k] * Y[k][j] + Y[ii][k] * M[k][j];
            AB[ii][j] = s;
        }
    float tr3 = (AB[0][0] + AB[1][1] + AB[2][2]) * (1.0f / 3.0f);
    float fro = 0.f;
#pragma unroll
    for (int ii = 0; ii < 3; ii++)
#pragma unroll
        for (int j = 0; j < 3; j++) fro += AB[ii][j] * AB[ii][j];
    float inv = __builtin_amdgcn_rcpf(fro + 1.0f);
    float (*L12)[12] = (float (*)[12])lo;
    L12[c][0] = tr3 * inv;
    L12[c][1] = 0.5f * (AB[0][1] - AB[1][0]) * inv;
    L12[c][2] = 0.5f * (AB[0][2] - AB[2][0]) * inv;
    L12[c][3] = 0.5f * (AB[1][2] - AB[2][1]) * inv;
    L12[c][4] = (AB[0][0] - tr3) * inv;
    L12[c][5] = (AB[1][1] - tr3) * inv;
    L12[c][6] = 0.5f * (AB[0][1] + AB[1][0]) * inv;
    L12[c][7] = 0.5f * (AB[0][2] + AB[2][0]) * inv;
    L12[c][8] = 0.5f * (AB[1][2] + AB[2][1]) * inv;
    __builtin_amdgcn_wave_barrier();
    int d = c;
    const float* W3 = WtT + 3 * 4096;
    const float* W4 = WtT + 4 * 4096;
    const float* W5 = WtT + 5 * 4096;
    float aI = 0, aA0 = 0, aA1 = 0, aA2 = 0, aS0 = 0, aS1 = 0, aS2 = 0, aS3 = 0, aS4 = 0;
    for (int cc = 0; cc < 64; ++cc) {
        float w3 = W3[cc * 64 + d], w4 = W4[cc * 64 + d], w5 = W5[cc * 64 + d];
        float4 L0 = *(const float4*)&L12[cc][0];
        float4 L1 = *(const float4*)&L12[cc][4];
        float L8 = L12[cc][8];
        aI  += w3 * L0.x;
        aA0 += w4 * L0.y; aA1 += w4 * L0.z; aA2 += w4 * L0.w;
        aS0 += w5 * L1.x; aS1 += w5 * L1.y; aS2 += w5 * L1.z;
        aS3 += w5 * L1.w; aS4 += w5 * L8;
    }
    float dX[3][3] = {
        { aI + aS0,   aA0 + aS2,  aA1 + aS3 },
        { -aA0 + aS2, aI + aS1,   aA2 + aS4 },
        { -aA1 + aS3, -aA2 + aS4, aI - aS0 - aS1 } };
    float D2[3][3];
#pragma unroll
    for (int ii = 0; ii < 3; ii++)
#pragma unroll
        for (int j = 0; j < 3; j++) {
            float s = 0.f;
#pragma unroll
            for (int k = 0; k < 3; k++) s += dX[ii][k] * dX[k][j];
            D2[ii][j] = s;
        }
    float x[9];
    __builtin_amdgcn_wave_barrier();
#pragma unroll
    for (int j = 0; j < 9; j++) x[j] = xs[d * 9 + j];
    float nrm = 0.f;
#pragma unroll
    for (int j = 0; j < 9; j++) nrm += x[j] * x[j];
    float xinv = __builtin_amdgcn_rcpf(nrm + 1.0f);
    __builtin_amdgcn_wave_barrier();
#pragma unroll
    for (int ii = 0; ii < 3; ii++)
#pragma unroll
        for (int j = 0; j < 3; j++)
            lo[d * 9 + ii * 3 + j] = x[ii * 3 + j] * xinv + dX[ii][j] + D2[ii][j];
    __builtin_amdgcn_wave_barrier();
#pragma unroll
    for (int ii = 0; ii < 9; ii++) out[(size_t)n * 576 + c + 64 * ii] = lo[c + 64 * ii];
}

extern "C" void kernel_launch(void* const* d_in, const int* in_sizes, int n_in,
                              void* d_out, int out_size, void* d_ws, size_t ws_size,
                              hipStream_t stream) {
    (void)in_sizes; (void)n_in; (void)out_size; (void)ws_size;
    const int* ei = (const int*)d_in[0];
    const float* ew = (const float*)d_in[1];
    const float* attr = (const float*)d_in[2];
    const float* X = (const float*)d_in[3];
    const float* Ws0 = (const float*)d_in[4];
    const float* bs0 = (const float*)d_in[5];
    const float* Ws1 = (const float*)d_in[6];
    const float* bs1 = (const float*)d_in[7];
    const float* Ws2 = (const float*)d_in[8];
    const float* bs2 = (const float*)d_in[9];
    const float* Wt0 = (const float*)d_in[10];
    const float* Wt1 = (const float*)d_in[11];
    const float* Wt2 = (const float*)d_in[12];
    const float* Wt3 = (const float*)d_in[13];
    const float* Wt4 = (const float*)d_in[14];
    const float* Wt5 = (const float*)d_in[15];
    float* ws = (float*)d_ws;
    int* ibase = (int*)(ws + OFF_INT);
    int* counts = ibase;
    int* cursor = ibase + NN;
    int* offsets = ibase + 2 * NN;
    int* dstp = ibase + 3 * NN + 1;
    unsigned short* PK = (unsigned short*)(ws + OFF_PK);
    unsigned int* IASu = (unsigned int*)(ws + OFF_IASH);
    unsigned short* eah = (unsigned short*)(ws + OFF_EAH);
    unsigned short* attrP = (unsigned short*)(ws + OFF_ATTRP);
    float* Cp = ws + OFF_CP;

    (void)hipMemsetAsync(counts, 0, 2 * NN * sizeof(int), stream);
    k_prep<<<(59584 + EE + 255) / 256, 256, 0, stream>>>(
        Wt0, Wt1, Wt2, Wt3, Wt4, Wt5, Ws0, Ws1, Ws2, bs2, ei,
        ws, PK, ws + OFF_B2P, counts);
    k_scan<<<1, 256, 0, stream>>>(counts, offsets);
    k_fill<<<(EE + 255) / 256, 256, 0, stream>>>(ei, offsets, attr, ew, cursor, dstp, attrP, Cp);
    k_mlpnp<<<EE / 128 + NN / 4, 256, 0, stream>>>(attrP, Cp, PK, bs0, bs1, ws + OFF_B2P,
                                                   X, ws, eah, IASu);
    k_aggout<<<NN / 2, 256, 0, stream>>>(offsets, dstp, eah, IASu, X, ws, (float*)d_out);
}